// Round 5
// baseline (550.643 us; speedup 1.0000x reference)
//
#include <hip/hip_runtime.h>
#include <hip/hip_bf16.h>
#include <hip/hip_cooperative_groups.h>

namespace cg = cooperative_groups;

#define D 96

typedef __attribute__((ext_vector_type(8))) short bf16x8;  // 8 bf16 (4 VGPRs)
typedef __attribute__((ext_vector_type(4))) float f32x4;

__device__ __forceinline__ short f2bf(float f)
{
    union { __hip_bfloat16 h; short s; } u;
    u.h = __float2bfloat16(f);
    return u.s;
}

__device__ __forceinline__ bf16x8 load_frag(const float* p)
{
    float4 lo = *(const float4*)p;
    float4 hi = *(const float4*)(p + 4);
    bf16x8 r;
    r[0] = f2bf(lo.x); r[1] = f2bf(lo.y); r[2] = f2bf(lo.z); r[3] = f2bf(lo.w);
    r[4] = f2bf(hi.x); r[5] = f2bf(hi.y); r[6] = f2bf(hi.z); r[7] = f2bf(hi.w);
    return r;
}

__device__ __forceinline__ float bf_lo(unsigned p) { return __uint_as_float(p << 16); }
__device__ __forceinline__ float bf_hi(unsigned p) { return __uint_as_float(p & 0xFFFF0000u); }

// ---------------------------------------------------------------------------
// P3a: CSR bucket fill (scattered writes; memory-latency bound, VALU idle)
// ---------------------------------------------------------------------------
__device__ __forceinline__ void fill_part(
    const int* __restrict__ src, const int* __restrict__ dst,
    int* __restrict__ cursor, int* __restrict__ csr,
    int E, int gtid, int gthreads)
{
    for (int e = gtid; e < E; e += gthreads) {
        int pos = atomicAdd(&cursor[dst[e]], 1);
        csr[pos] = src[e];
    }
}

// ---------------------------------------------------------------------------
// P3b: MFMA GEMM, no LDS (layouts verified in round 4):
// hl = x @ Wl^T (bf16), hr = x @ Wr^T (fp32, into d_out). One wave/16-row
// tile, K=96 in registers. A[m=lane&15][k=quad*8+j]; C/D col=lane&15,
// row=quad*4+reg.
// ---------------------------------------------------------------------------
__device__ __forceinline__ void gemm_part(
    const float* __restrict__ x, const float* __restrict__ Wl,
    const float* __restrict__ Wr, __hip_bfloat16* __restrict__ hl,
    float* __restrict__ hr, int N, int gwave, int gwaves, int lane)
{
    const int m = lane & 15, quad = lane >> 4;
    const int nrt = N / 16;                       // 3125 (exact)
    for (int t = gwave; t < nrt; t += gwaves) {
        int row = t * 16 + m;
        bf16x8 a[3];
        #pragma unroll
        for (int kt = 0; kt < 3; ++kt)
            a[kt] = load_frag(x + (size_t)row * D + kt * 32 + quad * 8);

        int orow = t * 16 + quad * 4;
        #pragma unroll
        for (int ct = 0; ct < 6; ++ct) {
            int wrow = ct * 16 + m;               // output col n
            const float* pl = Wl + (size_t)wrow * D + quad * 8;
            const float* pr = Wr + (size_t)wrow * D + quad * 8;
            f32x4 accl = {0.f, 0.f, 0.f, 0.f};
            f32x4 accr = {0.f, 0.f, 0.f, 0.f};
            #pragma unroll
            for (int kt = 0; kt < 3; ++kt) {
                bf16x8 b = load_frag(pl + kt * 32);
                accl = __builtin_amdgcn_mfma_f32_16x16x32_bf16(a[kt], b, accl, 0, 0, 0);
            }
            #pragma unroll
            for (int kt = 0; kt < 3; ++kt) {
                bf16x8 b = load_frag(pr + kt * 32);
                accr = __builtin_amdgcn_mfma_f32_16x16x32_bf16(a[kt], b, accr, 0, 0, 0);
            }
            int col = ct * 16 + m;
            #pragma unroll
            for (int r = 0; r < 4; ++r) {
                hl[(size_t)(orow + r) * D + col] = __float2bfloat16(accl[r]);
                hr[(size_t)(orow + r) * D + col] = accr[r];
            }
        }
    }
}

// ---------------------------------------------------------------------------
// Fused cooperative kernel: P0 zero -> P1 hist -> P2 alloc -> P3 fill||gemm
// -> P4 gather-mean + bias + relu (in place over hr in d_out).
// ---------------------------------------------------------------------------
__global__ __launch_bounds__(256, 4) void fused_kernel(
    const float* __restrict__ x, const int* __restrict__ src,
    const int* __restrict__ dst, const float* __restrict__ Wl,
    const float* __restrict__ bl, const float* __restrict__ Wr,
    float* __restrict__ out, int* __restrict__ wsi,
    __hip_bfloat16* __restrict__ hl, int N, int E)
{
    cg::grid_group grid = cg::this_grid();
    int* counts  = wsi;            // [N] ; counts[N] doubles as gcursor
    int* gcursor = wsi + N;
    int* beg     = gcursor + 1;    // [N]
    int* cursor  = beg + N;        // [N]
    int* csr     = cursor + N;     // [E]

    const int tid      = threadIdx.x;
    const int gthreads = gridDim.x * 256;
    const int gtid     = blockIdx.x * 256 + tid;
    const int lane     = tid & 63;
    const int gwave    = gtid >> 6;
    const int gwaves   = gthreads >> 6;

    __shared__ int wsum[4];
    __shared__ int base_s;

    // ---- P0: zero counts[0..N] (counts + gcursor) ----
    for (int i = gtid; i <= N; i += gthreads) counts[i] = 0;
    grid.sync();

    // ---- P1: histogram of dst ----
    for (int e = gtid; e < E; e += gthreads) atomicAdd(&counts[dst[e]], 1);
    grid.sync();

    // ---- P2: alloc — per-256-chunk block scan + one global atomic ----
    {
        const int nchunk = (N + 255) >> 8;
        const int wid = tid >> 6;
        for (int c = blockIdx.x; c < nchunk; c += gridDim.x) {
            int idx = c * 256 + tid;
            int v = (idx < N) ? counts[idx] : 0;
            int s = v;
            #pragma unroll
            for (int off = 1; off < 64; off <<= 1) {
                int t = __shfl_up(s, off);
                if (lane >= off) s += t;
            }
            if (lane == 63) wsum[wid] = s;
            __syncthreads();
            if (tid == 0)
                base_s = atomicAdd(gcursor, wsum[0] + wsum[1] + wsum[2] + wsum[3]);
            __syncthreads();
            int woff = 0;
            for (int w = 0; w < wid; ++w) woff += wsum[w];
            if (idx < N) {
                int b = base_s + woff + s - v;
                beg[idx] = b;
                cursor[idx] = b;
            }
            __syncthreads();   // wsum/base_s reused next chunk
        }
    }
    grid.sync();

    // ---- P3: fill (memory-bound) || gemm (compute-bound), parity-staggered ----
    if (blockIdx.x & 1) {
        gemm_part(x, Wl, Wr, hl, out, N, gwave, gwaves, lane);
        fill_part(src, dst, cursor, csr, E, gtid, gthreads);
    } else {
        fill_part(src, dst, cursor, csr, E, gtid, gthreads);
        gemm_part(x, Wl, Wr, hl, out, N, gwave, gwaves, lane);
    }
    grid.sync();

    // ---- P4: gather-mean of hl + bias + relu, in place over hr (=out) ----
    {
        const bool active = lane < 48;
        for (int node = gwave; node < N; node += gwaves) {
            int b = beg[node];
            int deg = counts[node];
            int end = b + deg;
            float a0 = 0.f, a1 = 0.f;
            int j = b;
            for (; j + 2 <= end; j += 2) {
                int s0 = csr[j];
                int s1 = csr[j + 1];
                if (active) {
                    unsigned p0 = *(const unsigned*)((const char*)hl + (size_t)s0 * 192 + lane * 4);
                    unsigned p1 = *(const unsigned*)((const char*)hl + (size_t)s1 * 192 + lane * 4);
                    a0 += bf_lo(p0) + bf_lo(p1);
                    a1 += bf_hi(p0) + bf_hi(p1);
                }
            }
            if (j < end) {
                int s0 = csr[j];
                if (active) {
                    unsigned p0 = *(const unsigned*)((const char*)hl + (size_t)s0 * 192 + lane * 4);
                    a0 += bf_lo(p0);
                    a1 += bf_hi(p0);
                }
            }
            if (active) {
                float inv = 1.0f / fmaxf((float)deg, 1.0f);
                int o = 2 * lane;
                size_t base = (size_t)node * D + o;
                float v0 = a0 * inv + bl[o]     + out[base];
                float v1 = a1 * inv + bl[o + 1] + out[base + 1];
                out[base]     = fmaxf(v0, 0.f);
                out[base + 1] = fmaxf(v1, 0.f);
            }
        }
    }
}

extern "C" void kernel_launch(void* const* d_in, const int* in_sizes, int n_in,
                              void* d_out, int out_size, void* d_ws, size_t ws_size,
                              hipStream_t stream)
{
    const float* x  = (const float*)d_in[0];
    const int*   ei = (const int*)d_in[1];   // [2, E]: src row then dst row
    const float* Wl = (const float*)d_in[2];
    const float* bl = (const float*)d_in[3];
    const float* Wr = (const float*)d_in[4];
    float* out = (float*)d_out;

    int N = in_sizes[0] / D;   // 50000
    int E = in_sizes[1] / 2;   // 800000
    const int* src = ei;
    const int* dst = ei + E;

    // ws: counts[N], gcursor[1], beg[N], cursor[N], csr[E], hl[N*D] bf16
    int* wsi = (int*)d_ws;
    __hip_bfloat16* hl = (__hip_bfloat16*)(wsi + (size_t)3 * N + 1 + E);

    // size the cooperative grid from actual occupancy (host-side query;
    // runs only during capture, not in timed replays)
    int maxb = 0;
    if (hipOccupancyMaxActiveBlocksPerMultiprocessor(&maxb, fused_kernel, 256, 0)
            != hipSuccess || maxb < 1)
        maxb = 1;
    int dev = 0;
    hipGetDevice(&dev);
    hipDeviceProp_t prop;
    int ncu = 256;
    if (hipGetDeviceProperties(&prop, dev) == hipSuccess)
        ncu = prop.multiProcessorCount;
    int grid = maxb * ncu;
    if (grid > 4096) grid = 4096;

    void* args[] = { (void*)&x, (void*)&src, (void*)&dst, (void*)&Wl,
                     (void*)&bl, (void*)&Wr, (void*)&out, (void*)&wsi,
                     (void*)&hl, (void*)&N, (void*)&E };
    hipLaunchCooperativeKernel((void*)fused_kernel, dim3(grid), dim3(256),
                               args, 0, stream);
}

// Round 6
// 228.882 us; speedup vs baseline: 2.4058x; 2.4058x over previous
//
#include <hip/hip_runtime.h>
#include <hip/hip_bf16.h>

#define D 96
#define CAP 64          // max tracked degree; overflow list handles the rest
#define OVF_MAX 65536   // overflow capacity (empty for this graph)

typedef __attribute__((ext_vector_type(8))) short bf16x8;  // 8 bf16 (4 VGPRs)
typedef __attribute__((ext_vector_type(4))) float f32x4;

__device__ __forceinline__ short f2bf(float f)
{
    union { __hip_bfloat16 h; short s; } u;
    u.h = __float2bfloat16(f);
    return u.s;
}

__device__ __forceinline__ bf16x8 load_frag(const float* p)
{
    float4 lo = *(const float4*)p;
    float4 hi = *(const float4*)(p + 4);
    bf16x8 r;
    r[0] = f2bf(lo.x); r[1] = f2bf(lo.y); r[2] = f2bf(lo.z); r[3] = f2bf(lo.w);
    r[4] = f2bf(hi.x); r[5] = f2bf(hi.y); r[6] = f2bf(hi.z); r[7] = f2bf(hi.w);
    return r;
}

__device__ __forceinline__ float bf_lo(unsigned p) { return __uint_as_float(p << 16); }
__device__ __forceinline__ float bf_hi(unsigned p) { return __uint_as_float(p & 0xFFFF0000u); }

// ---------------------------------------------------------------------------
// K1: MFMA GEMM (no LDS) + zero cnt. hl = x@Wl^T (bf16, SLICE-BLOCKED layout
// hl[s][node][c], s=col/32, c=col%32 -> 64B rows per slice), hr = x@Wr^T
// (fp32, into d_out). One wave per 16-row tile, K=96 in registers.
// Layouts verified R4: A[m=lane&15][k=quad*8+j]; C/D col=lane&15, row=quad*4+reg.
// ---------------------------------------------------------------------------
__global__ __launch_bounds__(256) void gemm_zero_kernel(
    const float* __restrict__ x, const float* __restrict__ Wl,
    const float* __restrict__ Wr, __hip_bfloat16* __restrict__ hl,
    float* __restrict__ hr, int* __restrict__ cnt, int N)
{
    const int gid = blockIdx.x * 256 + threadIdx.x;
    // zero cnt[0..N]  (cnt[N] doubles as the overflow counter)
    for (int i = gid; i <= N; i += gridDim.x * 256) cnt[i] = 0;

    const int gwave = gid >> 6;
    const int nrt = N / 16;                      // 3125 (exact)
    if (gwave >= nrt) return;
    const int lane = threadIdx.x & 63;
    const int m = lane & 15, quad = lane >> 4;
    const int row = gwave * 16 + m;

    bf16x8 a[3];
    #pragma unroll
    for (int kt = 0; kt < 3; ++kt)
        a[kt] = load_frag(x + (size_t)row * D + kt * 32 + quad * 8);

    const int orow = gwave * 16 + quad * 4;
    #pragma unroll
    for (int ct = 0; ct < 6; ++ct) {
        int wrow = ct * 16 + m;                  // output col n
        const float* pl = Wl + (size_t)wrow * D + quad * 8;
        const float* pr = Wr + (size_t)wrow * D + quad * 8;
        f32x4 accl = {0.f, 0.f, 0.f, 0.f};
        f32x4 accr = {0.f, 0.f, 0.f, 0.f};
        #pragma unroll
        for (int kt = 0; kt < 3; ++kt) {
            bf16x8 b = load_frag(pl + kt * 32);
            accl = __builtin_amdgcn_mfma_f32_16x16x32_bf16(a[kt], b, accl, 0, 0, 0);
        }
        #pragma unroll
        for (int kt = 0; kt < 3; ++kt) {
            bf16x8 b = load_frag(pr + kt * 32);
            accr = __builtin_amdgcn_mfma_f32_16x16x32_bf16(a[kt], b, accr, 0, 0, 0);
        }
        int col = ct * 16 + m;
        int sl = col >> 5, c = col & 31;         // slice, col-in-slice
        #pragma unroll
        for (int r = 0; r < 4; ++r) {
            int node = orow + r;
            hl[((size_t)sl * N + node) * 32 + c] = __float2bfloat16(accl[r]);
            hr[(size_t)node * D + col] = accr[r];
        }
    }
}

// ---------------------------------------------------------------------------
// K2: slot fill, XCD-partitioned by dst range. blockIdx&7 selects a dst
// range of N/8 nodes (heuristic: %8 ~ XCD id), so slot/cnt lines are only
// dirtied by one XCD's L2 (R4 fill: 52 MB write-thrash from all-XCD dirty
// lines). Each group scans all edges, filters by range. uint16 slots.
// ---------------------------------------------------------------------------
__global__ __launch_bounds__(256) void fill_kernel(
    const int* __restrict__ src, const int* __restrict__ dst,
    int* __restrict__ cnt, unsigned short* __restrict__ slot,
    int* __restrict__ ovf, int E, int N)
{
    const int g  = blockIdx.x & 7;
    const int w  = blockIdx.x >> 3;
    const int NW = gridDim.x >> 3;
    const int CS = (E + NW - 1) / NW;
    const int n8 = N >> 3;                       // 6250 (N % 8 == 0)
    const int lo = g * n8;
    const int hi = (g == 7) ? N : lo + n8;
    const int base = w * CS;
    const int lim = min(CS, E - base);
    for (int i = threadIdx.x; i < lim; i += 256) {
        int e = base + i;
        int d = dst[e];
        if (d >= lo && d < hi) {
            int pos = atomicAdd(&cnt[d], 1);
            if (pos < CAP) {
                slot[(size_t)d * CAP + pos] = (unsigned short)src[e];
            } else {
                int o = atomicAdd(&cnt[N], 1);
                if (o < OVF_MAX) { ovf[2 * o] = d; ovf[2 * o + 1] = src[e]; }
            }
        }
    }
}

// ---------------------------------------------------------------------------
// K3: gather-mean + bias + relu, feature-sliced. Block-id-major slice order
// (blocks [0,4096)->slice0, etc.) => co-resident blocks share one 3.2 MB
// slice, fitting per-XCD L2 (R4: 9.6 MB working set thrashed 4 MB L2,
// FETCH 91 MB). Wave = 1 node: quad q handles neighbor j+q, 16 lanes cover
// the 32-feature slice as 16 uints; cross-quad shfl_xor reduce.
// ---------------------------------------------------------------------------
__global__ __launch_bounds__(256) void agg_kernel(
    const __hip_bfloat16* __restrict__ hl, const int* __restrict__ cnt,
    const unsigned short* __restrict__ slot, const int* __restrict__ ovf,
    const float* __restrict__ bl, float* __restrict__ out, int N)
{
    const int lane = threadIdx.x & 63;
    const int wv = threadIdx.x >> 6;
    const int s = blockIdx.x >> 12;              // slice 0..2 (4096 blocks each)
    const int bb = blockIdx.x & 4095;
    const int q = lane >> 4, f = lane & 15;
    const int ovfn = min(cnt[N], OVF_MAX);
    const __hip_bfloat16* hs = hl + (size_t)s * N * 32;

    for (int n = bb * 4 + wv; n < N; n += 4096 * 4) {
        int deg = cnt[n];
        int dc = min(deg, CAP);
        float a0 = 0.f, a1 = 0.f;
        const unsigned short* sl = slot + (size_t)n * CAP;
        for (int j0 = 0; j0 < dc; j0 += 4) {
            int idx = j0 + q;
            if (idx < dc) {
                int nb = sl[idx];
                unsigned p = *(const unsigned*)(hs + (size_t)nb * 32 + 2 * f);
                a0 += bf_lo(p);
                a1 += bf_hi(p);
            }
        }
        // reduce across quads (q is lane bits 4-5)
        a0 += __shfl_xor(a0, 16); a0 += __shfl_xor(a0, 32);
        a1 += __shfl_xor(a1, 16); a1 += __shfl_xor(a1, 32);
        if (q == 0) {
            // overflow edges (empty for this graph; exactness guard)
            for (int k = 0; k < ovfn; ++k) {
                if (ovf[2 * k] == n) {
                    int nb = ovf[2 * k + 1];
                    unsigned p = *(const unsigned*)(hs + (size_t)nb * 32 + 2 * f);
                    a0 += bf_lo(p);
                    a1 += bf_hi(p);
                }
            }
            float inv = 1.0f / fmaxf((float)deg, 1.0f);
            int o = s * 32 + 2 * f;
            size_t b = (size_t)n * D + o;
            float v0 = a0 * inv + bl[o]     + out[b];
            float v1 = a1 * inv + bl[o + 1] + out[b + 1];
            out[b]     = fmaxf(v0, 0.f);
            out[b + 1] = fmaxf(v1, 0.f);
        }
    }
}

extern "C" void kernel_launch(void* const* d_in, const int* in_sizes, int n_in,
                              void* d_out, int out_size, void* d_ws, size_t ws_size,
                              hipStream_t stream)
{
    const float* x  = (const float*)d_in[0];
    const int*   ei = (const int*)d_in[1];   // [2, E]: src row then dst row
    const float* Wl = (const float*)d_in[2];
    const float* bl = (const float*)d_in[3];
    const float* Wr = (const float*)d_in[4];
    float* out = (float*)d_out;

    const int N = in_sizes[0] / D;   // 50000
    const int E = in_sizes[1] / 2;   // 800000
    const int* src = ei;
    const int* dst = ei + E;

    // ws: cnt[N+1], ovf[2*OVF_MAX], slot[N*CAP] u16, hl[3*N*32] bf16 (~16.7MB)
    int* cnt = (int*)d_ws;
    int* ovf = cnt + (N + 1);
    unsigned short* slot = (unsigned short*)(ovf + 2 * OVF_MAX);
    __hip_bfloat16* hl = (__hip_bfloat16*)(slot + (size_t)N * CAP);

    const int gblocks = (N / 16 + 3) / 4;        // 782 (4 waves/block)
    gemm_zero_kernel<<<gblocks, 256, 0, stream>>>(x, Wl, Wr, hl, out, cnt, N);

    fill_kernel<<<4096, 256, 0, stream>>>(src, dst, cnt, slot, ovf, E, N);

    agg_kernel<<<3 * 4096, 256, 0, stream>>>(hl, cnt, slot, ovf, bl, out, N);
}

// Round 7
// 206.196 us; speedup vs baseline: 2.6705x; 1.1100x over previous
//
#include <hip/hip_runtime.h>
#include <hip/hip_bf16.h>

#define D 96
#define CAP 64          // max tracked degree; slots 32..63 via rare tail loop
#define OVF_MAX 65536   // overflow list capacity (deg > CAP; empty here)
#define FILLB 2048      // fill-role blocks in fused kernel (multiple of 8)

typedef __attribute__((ext_vector_type(8))) short bf16x8;  // 8 bf16 (4 VGPRs)
typedef __attribute__((ext_vector_type(4))) float f32x4;

__device__ __forceinline__ short f2bf(float f)
{
    union { __hip_bfloat16 h; short s; } u;
    u.h = __float2bfloat16(f);
    return u.s;
}

__device__ __forceinline__ bf16x8 load_frag(const float* p)
{
    float4 lo = *(const float4*)p;
    float4 hi = *(const float4*)(p + 4);
    bf16x8 r;
    r[0] = f2bf(lo.x); r[1] = f2bf(lo.y); r[2] = f2bf(lo.z); r[3] = f2bf(lo.w);
    r[4] = f2bf(hi.x); r[5] = f2bf(hi.y); r[6] = f2bf(hi.z); r[7] = f2bf(hi.w);
    return r;
}

__device__ __forceinline__ float bf_lo(unsigned p) { return __uint_as_float(p << 16); }
__device__ __forceinline__ float bf_hi(unsigned p) { return __uint_as_float(p & 0xFFFF0000u); }

// ---------------------------------------------------------------------------
// K1 (fused): block-role split. Blocks [0,FILLB): slot fill, XCD-partitioned
// by dst range (R6: confines dirty slot lines to one XCD's L2). Remaining
// blocks: MFMA GEMM (no LDS), hl = x@Wl^T (bf16, slice-blocked hl[s][n][c]),
// hr = x@Wr^T (fp32 -> d_out). The two roles are independent; fill's memory
// shadow absorbs gemm's compute. cnt zeroed by memsetAsync beforehand.
// ---------------------------------------------------------------------------
__global__ __launch_bounds__(256) void fused_gf_kernel(
    const float* __restrict__ x, const int* __restrict__ src,
    const int* __restrict__ dst, const float* __restrict__ Wl,
    const float* __restrict__ Wr, __hip_bfloat16* __restrict__ hl,
    float* __restrict__ hr, int* __restrict__ cnt,
    unsigned short* __restrict__ slot, int* __restrict__ ovf,
    int N, int E)
{
    if (blockIdx.x < FILLB) {
        // ---- fill role ----
        const int fb = blockIdx.x;
        const int g  = fb & 7;
        const int w  = fb >> 3;
        const int NW = FILLB >> 3;               // 256 chunks
        const int CS = (E + NW - 1) / NW;
        const int n8 = N >> 3;
        const int lo = g * n8;
        const int hi = (g == 7) ? N : lo + n8;
        const int base = w * CS;
        int lim = E - base; if (lim > CS) lim = CS; if (lim < 0) lim = 0;
        for (int i = threadIdx.x; i < lim; i += 256) {
            int e = base + i;
            int d  = dst[e];
            int sv = src[e];                     // unconditional: keep streaming
            if (d >= lo && d < hi) {
                int pos = atomicAdd(&cnt[d], 1);
                if (pos < CAP) {
                    slot[(size_t)d * CAP + pos] = (unsigned short)sv;
                } else {
                    int o = atomicAdd(&cnt[N], 1);
                    if (o < OVF_MAX) { ovf[2 * o] = d; ovf[2 * o + 1] = sv; }
                }
            }
        }
        return;
    }

    // ---- gemm role (layouts verified R4: A[m=lane&15][k=quad*8+j];
    //      C/D col=lane&15, row=quad*4+reg) ----
    const int gb = blockIdx.x - FILLB;
    const int gwave = (gb * 256 + threadIdx.x) >> 6;
    const int nrt = N / 16;                      // 3125 (exact)
    if (gwave >= nrt) return;
    const int lane = threadIdx.x & 63;
    const int m = lane & 15, quad = lane >> 4;
    const int row = gwave * 16 + m;

    bf16x8 a[3];
    #pragma unroll
    for (int kt = 0; kt < 3; ++kt)
        a[kt] = load_frag(x + (size_t)row * D + kt * 32 + quad * 8);

    const int orow = gwave * 16 + quad * 4;
    #pragma unroll
    for (int ct = 0; ct < 6; ++ct) {
        int wrow = ct * 16 + m;                  // output col n
        const float* pl = Wl + (size_t)wrow * D + quad * 8;
        const float* pr = Wr + (size_t)wrow * D + quad * 8;
        f32x4 accl = {0.f, 0.f, 0.f, 0.f};
        f32x4 accr = {0.f, 0.f, 0.f, 0.f};
        #pragma unroll
        for (int kt = 0; kt < 3; ++kt) {
            bf16x8 b = load_frag(pl + kt * 32);
            accl = __builtin_amdgcn_mfma_f32_16x16x32_bf16(a[kt], b, accl, 0, 0, 0);
        }
        #pragma unroll
        for (int kt = 0; kt < 3; ++kt) {
            bf16x8 b = load_frag(pr + kt * 32);
            accr = __builtin_amdgcn_mfma_f32_16x16x32_bf16(a[kt], b, accr, 0, 0, 0);
        }
        int col = ct * 16 + m;
        int sl = col >> 5, c = col & 31;         // slice, col-in-slice
        #pragma unroll
        for (int r = 0; r < 4; ++r) {
            int node = orow + r;
            hl[((size_t)sl * N + node) * 32 + c] = __float2bfloat16(accl[r]);
            hr[(size_t)node * D + col] = accr[r];
        }
    }
}

// ---------------------------------------------------------------------------
// K2: gather-mean + bias + relu, feature-sliced (3 x 32 features; 64 B rows;
// block-id-major slice order keeps one 3.2 MB slice per XCD L2). Wave = node.
// NEW vs R6: slot row preloaded in ONE 64 B coalesced read (lanes 0-15),
// neighbor ids distributed via shfl -> all hl gathers are address-independent
// and unconditional (nb masked to 0, contribution masked by multiply), so
// unroll-4 keeps ~16 loads in flight (R6: serial 2-load chain, VALUBusy 24%).
// ---------------------------------------------------------------------------
__global__ __launch_bounds__(256) void agg_kernel(
    const __hip_bfloat16* __restrict__ hl, const int* __restrict__ cnt,
    const unsigned short* __restrict__ slot, const int* __restrict__ ovf,
    const float* __restrict__ bl, float* __restrict__ out, int N)
{
    const int lane = threadIdx.x & 63;
    const int wv = threadIdx.x >> 6;
    const int s  = blockIdx.x >> 12;             // slice 0..2 (4096 blocks each)
    const int bb = blockIdx.x & 4095;
    const int q = lane >> 4, f = lane & 15;
    const int ovfn = min(cnt[N], OVF_MAX);
    const __hip_bfloat16* hs = hl + (size_t)s * N * 32;
    const int o = s * 32 + 2 * f;
    const float b0 = bl[o], b1 = bl[o + 1];      // hoisted (thread-constant)

    for (int n = bb * 4 + wv; n < N; n += 4096 * 4) {
        int deg = cnt[n];
        int dc = min(deg, CAP);
        const unsigned* sp = (const unsigned*)(slot + (size_t)n * CAP);
        unsigned sid = (lane < 16) ? sp[lane] : 0u;  // 32 ids, one 64B line
        float a0 = 0.f, a1 = 0.f;
        int dp = min(dc, 32);
        #pragma unroll 4
        for (int j0 = 0; j0 < dp; j0 += 4) {
            int idx = j0 + q;
            unsigned dw = __shfl(sid, idx >> 1);
            int nb = (idx & 1) ? (int)(dw >> 16) : (int)(dw & 0xFFFFu);
            bool act = idx < dp;
            nb = act ? nb : 0;                   // keep load in-bounds & unconditional
            unsigned p = *(const unsigned*)(hs + (size_t)nb * 32 + 2 * f);
            float mk = act ? 1.f : 0.f;
            a0 += mk * bf_lo(p);
            a1 += mk * bf_hi(p);
        }
        if (dc > 32) {                           // rare (Poisson(16): ~1e-4)
            for (int idx = 32 + q; idx < dc; idx += 4) {
                unsigned dw = sp[idx >> 1];
                int nb = (idx & 1) ? (int)(dw >> 16) : (int)(dw & 0xFFFFu);
                unsigned p = *(const unsigned*)(hs + (size_t)nb * 32 + 2 * f);
                a0 += bf_lo(p);
                a1 += bf_hi(p);
            }
        }
        // reduce across quads (q = lane bits 4-5)
        a0 += __shfl_xor(a0, 16); a0 += __shfl_xor(a0, 32);
        a1 += __shfl_xor(a1, 16); a1 += __shfl_xor(a1, 32);
        if (q == 0) {
            if (ovfn) {                          // exactness guard, empty here
                for (int k = 0; k < ovfn; ++k) {
                    if (ovf[2 * k] == n) {
                        int nb = ovf[2 * k + 1];
                        unsigned p = *(const unsigned*)(hs + (size_t)nb * 32 + 2 * f);
                        a0 += bf_lo(p);
                        a1 += bf_hi(p);
                    }
                }
            }
            float inv = 1.0f / fmaxf((float)deg, 1.0f);
            size_t b = (size_t)n * D + o;
            float v0 = a0 * inv + b0 + out[b];
            float v1 = a1 * inv + b1 + out[b + 1];
            out[b]     = fmaxf(v0, 0.f);
            out[b + 1] = fmaxf(v1, 0.f);
        }
    }
}

extern "C" void kernel_launch(void* const* d_in, const int* in_sizes, int n_in,
                              void* d_out, int out_size, void* d_ws, size_t ws_size,
                              hipStream_t stream)
{
    const float* x  = (const float*)d_in[0];
    const int*   ei = (const int*)d_in[1];   // [2, E]: src row then dst row
    const float* Wl = (const float*)d_in[2];
    const float* bl = (const float*)d_in[3];
    const float* Wr = (const float*)d_in[4];
    float* out = (float*)d_out;

    const int N = in_sizes[0] / D;   // 50000
    const int E = in_sizes[1] / 2;   // 800000
    const int* src = ei;
    const int* dst = ei + E;

    // ws: cnt[N+1], ovf[2*OVF_MAX], slot[N*CAP] u16, hl[3*N*32] bf16 (~16.7MB)
    int* cnt = (int*)d_ws;
    int* ovf = cnt + (N + 1);
    unsigned short* slot = (unsigned short*)(ovf + 2 * OVF_MAX);
    __hip_bfloat16* hl = (__hip_bfloat16*)(slot + (size_t)N * CAP);

    hipMemsetAsync(cnt, 0, (size_t)(N + 1) * sizeof(int), stream);

    const int gemmb = (N / 16 + 3) / 4;          // 782 gemm blocks
    fused_gf_kernel<<<FILLB + gemmb, 256, 0, stream>>>(
        x, src, dst, Wl, Wr, hl, out, cnt, slot, ovf, N, E);

    agg_kernel<<<3 * 4096, 256, 0, stream>>>(hl, cnt, slot, ovf, bl, out, N);
}

// Round 8
// 204.934 us; speedup vs baseline: 2.6869x; 1.0062x over previous
//
#include <hip/hip_runtime.h>
#include <hip/hip_bf16.h>

#define D 96
#define CAP 64          // max tracked degree; slots 32..63 via rare tail loop
#define OVF_MAX 65536   // overflow list capacity (deg > CAP; empty here)
#define FILLB 4096      // fill-role blocks in fused kernel (multiple of 8)

typedef __attribute__((ext_vector_type(8))) short bf16x8;  // 8 bf16 (4 VGPRs)
typedef __attribute__((ext_vector_type(4))) float f32x4;

__device__ __forceinline__ short f2bf(float f)
{
    union { __hip_bfloat16 h; short s; } u;
    u.h = __float2bfloat16(f);
    return u.s;
}

__device__ __forceinline__ bf16x8 load_frag(const float* p)
{
    float4 lo = *(const float4*)p;
    float4 hi = *(const float4*)(p + 4);
    bf16x8 r;
    r[0] = f2bf(lo.x); r[1] = f2bf(lo.y); r[2] = f2bf(lo.z); r[3] = f2bf(lo.w);
    r[4] = f2bf(hi.x); r[5] = f2bf(hi.y); r[6] = f2bf(hi.z); r[7] = f2bf(hi.w);
    return r;
}

__device__ __forceinline__ float bf_lo(unsigned p) { return __uint_as_float(p << 16); }
__device__ __forceinline__ float bf_hi(unsigned p) { return __uint_as_float(p & 0xFFFF0000u); }

// ---------------------------------------------------------------------------
// K1 (fused): block-role split. Blocks [0,FILLB): slot fill, XCD-partitioned
// by dst range. R8: dst/src loads are NONTEMPORAL (R7: 51 MB of streaming
// reads evicted dirty slot lines from L2 -> 29 MB writeback thrash); src load
// made conditional; FILLB doubled for atomic-latency hiding.
// Remaining blocks: MFMA GEMM (no LDS), hl = x@Wl^T (bf16, slice-blocked
// hl[s][n][c]), hr = x@Wr^T (fp32 -> d_out).
// ---------------------------------------------------------------------------
__global__ __launch_bounds__(256) void fused_gf_kernel(
    const float* __restrict__ x, const int* __restrict__ src,
    const int* __restrict__ dst, const float* __restrict__ Wl,
    const float* __restrict__ Wr, __hip_bfloat16* __restrict__ hl,
    float* __restrict__ hr, int* __restrict__ cnt,
    unsigned short* __restrict__ slot, int* __restrict__ ovf,
    int N, int E)
{
    if (blockIdx.x < FILLB) {
        // ---- fill role ----
        const int fb = blockIdx.x;
        const int g  = fb & 7;
        const int w  = fb >> 3;
        const int NW = FILLB >> 3;               // 512 chunks per group
        const int CS = (E + NW - 1) / NW;
        const int n8 = N >> 3;
        const int lo = g * n8;
        const int hi = (g == 7) ? N : lo + n8;
        const int base = w * CS;
        int lim = E - base; if (lim > CS) lim = CS; if (lim < 0) lim = 0;
        #pragma unroll 4
        for (int i = threadIdx.x; i < lim; i += 256) {
            int e = base + i;
            int d = __builtin_nontemporal_load(dst + e);
            if (d >= lo && d < hi) {
                int sv = __builtin_nontemporal_load(src + e);
                int pos = atomicAdd(&cnt[d], 1);
                if (pos < CAP) {
                    slot[(size_t)d * CAP + pos] = (unsigned short)sv;
                } else {
                    int o = atomicAdd(&cnt[N], 1);
                    if (o < OVF_MAX) { ovf[2 * o] = d; ovf[2 * o + 1] = sv; }
                }
            }
        }
        return;
    }

    // ---- gemm role (layouts verified R4: A[m=lane&15][k=quad*8+j];
    //      C/D col=lane&15, row=quad*4+reg) ----
    const int gb = blockIdx.x - FILLB;
    const int gwave = (gb * 256 + threadIdx.x) >> 6;
    const int nrt = N / 16;                      // 3125 (exact)
    if (gwave >= nrt) return;
    const int lane = threadIdx.x & 63;
    const int m = lane & 15, quad = lane >> 4;
    const int row = gwave * 16 + m;

    bf16x8 a[3];
    #pragma unroll
    for (int kt = 0; kt < 3; ++kt)
        a[kt] = load_frag(x + (size_t)row * D + kt * 32 + quad * 8);

    const int orow = gwave * 16 + quad * 4;
    #pragma unroll
    for (int ct = 0; ct < 6; ++ct) {
        int wrow = ct * 16 + m;                  // output col n
        const float* pl = Wl + (size_t)wrow * D + quad * 8;
        const float* pr = Wr + (size_t)wrow * D + quad * 8;
        f32x4 accl = {0.f, 0.f, 0.f, 0.f};
        f32x4 accr = {0.f, 0.f, 0.f, 0.f};
        #pragma unroll
        for (int kt = 0; kt < 3; ++kt) {
            bf16x8 b = load_frag(pl + kt * 32);
            accl = __builtin_amdgcn_mfma_f32_16x16x32_bf16(a[kt], b, accl, 0, 0, 0);
        }
        #pragma unroll
        for (int kt = 0; kt < 3; ++kt) {
            bf16x8 b = load_frag(pr + kt * 32);
            accr = __builtin_amdgcn_mfma_f32_16x16x32_bf16(a[kt], b, accr, 0, 0, 0);
        }
        int col = ct * 16 + m;
        int sl = col >> 5, c = col & 31;         // slice, col-in-slice
        #pragma unroll
        for (int r = 0; r < 4; ++r) {
            int node = orow + r;
            hl[((size_t)sl * N + node) * 32 + c] = __float2bfloat16(accl[r]);
            hr[(size_t)node * D + col] = accr[r];
        }
    }
}

// ---------------------------------------------------------------------------
// K2: gather-mean + bias + relu, feature-sliced (3 x 32 features, 64 B rows;
// block-id-major slice order keeps one 3.2 MB slice per XCD L2).
// R8: TWO nodes per wave (lane halves own independent nodes) -> 2x memory-
// level parallelism. Slot rows preloaded coalesced (lanes 0-15 -> node A,
// 32-47 -> node B), ids distributed via shfl; gathers unconditional
// (masked by multiply) so the unroll keeps loads in flight.
// ---------------------------------------------------------------------------
__global__ __launch_bounds__(256) void agg_kernel(
    const __hip_bfloat16* __restrict__ hl, const int* __restrict__ cnt,
    const unsigned short* __restrict__ slot, const int* __restrict__ ovf,
    const float* __restrict__ bl, float* __restrict__ out, int N)
{
    const int lane = threadIdx.x & 63;
    const int wv = threadIdx.x >> 6;
    const int s  = blockIdx.x >> 12;             // slice 0..2 (4096 blocks each)
    const int bb = blockIdx.x & 4095;
    const int h  = lane >> 5;                    // half: 0 = node A, 1 = node B
    const int sq = (lane >> 4) & 1;              // sub-quad within half
    const int f  = lane & 15;
    const int ovfn = min(cnt[N], OVF_MAX);
    const __hip_bfloat16* hs = hl + (size_t)s * N * 32;
    const int o = s * 32 + 2 * f;
    const float b0 = bl[o], b1 = bl[o + 1];      // hoisted (thread-constant)

    for (int n0 = bb * 8 + wv * 2; n0 < N; n0 += 4096 * 8) {
        int n = n0 + h;                          // per-half node
        bool valid = n < N;
        int nc = valid ? n : (N - 1);            // clamped for safe addressing
        int deg = valid ? cnt[nc] : 0;
        int dc = min(deg, CAP);
        int dp = min(dc, 32);
        const unsigned* sp = (const unsigned*)(slot + (size_t)nc * CAP);
        unsigned sid = ((lane & 31) < 16) ? sp[f] : 0u;   // 32 ids / node, 64B line
        // wave-uniform loop bound = max(dp_A, dp_B)
        int um = max(dp, __shfl(dp, lane ^ 32));
        float a0 = 0.f, a1 = 0.f;
        #pragma unroll 4
        for (int j = 0; j < um; j += 2) {
            int idx = j + sq;
            unsigned dw = __shfl(sid, (lane & 32) + (j >> 1));
            bool act = idx < dp;
            int nb = act ? (sq ? (int)(dw >> 16) : (int)(dw & 0xFFFFu)) : 0;
            unsigned p = *(const unsigned*)(hs + (size_t)nb * 32 + 2 * f);
            float mk = act ? 1.f : 0.f;
            a0 += mk * bf_lo(p);
            a1 += mk * bf_hi(p);
        }
        if (dc > 32) {                           // rare (Poisson(16): ~1e-4)
            for (int idx = 32 + sq; idx < dc; idx += 2) {
                unsigned dw = sp[idx >> 1];
                int nb = sq ? (int)(dw >> 16) : (int)(dw & 0xFFFFu);
                unsigned p = *(const unsigned*)(hs + (size_t)nb * 32 + 2 * f);
                a0 += bf_lo(p);
                a1 += bf_hi(p);
            }
        }
        // reduce across the two sub-quads of each half (lane bit 4 only)
        a0 += __shfl_xor(a0, 16);
        a1 += __shfl_xor(a1, 16);
        if (sq == 0 && valid) {
            if (ovfn) {                          // exactness guard, empty here
                for (int k = 0; k < ovfn; ++k) {
                    if (ovf[2 * k] == n) {
                        int nb = ovf[2 * k + 1];
                        unsigned p = *(const unsigned*)(hs + (size_t)nb * 32 + 2 * f);
                        a0 += bf_lo(p);
                        a1 += bf_hi(p);
                    }
                }
            }
            float inv = 1.0f / fmaxf((float)deg, 1.0f);
            size_t b = (size_t)n * D + o;
            float v0 = a0 * inv + b0 + out[b];
            float v1 = a1 * inv + b1 + out[b + 1];
            out[b]     = fmaxf(v0, 0.f);
            out[b + 1] = fmaxf(v1, 0.f);
        }
    }
}

extern "C" void kernel_launch(void* const* d_in, const int* in_sizes, int n_in,
                              void* d_out, int out_size, void* d_ws, size_t ws_size,
                              hipStream_t stream)
{
    const float* x  = (const float*)d_in[0];
    const int*   ei = (const int*)d_in[1];   // [2, E]: src row then dst row
    const float* Wl = (const float*)d_in[2];
    const float* bl = (const float*)d_in[3];
    const float* Wr = (const float*)d_in[4];
    float* out = (float*)d_out;

    const int N = in_sizes[0] / D;   // 50000
    const int E = in_sizes[1] / 2;   // 800000
    const int* src = ei;
    const int* dst = ei + E;

    // ws: cnt[N+1], ovf[2*OVF_MAX], slot[N*CAP] u16, hl[3*N*32] bf16 (~16.7MB)
    int* cnt = (int*)d_ws;
    int* ovf = cnt + (N + 1);
    unsigned short* slot = (unsigned short*)(ovf + 2 * OVF_MAX);
    __hip_bfloat16* hl = (__hip_bfloat16*)(slot + (size_t)N * CAP);

    hipMemsetAsync(cnt, 0, (size_t)(N + 1) * sizeof(int), stream);

    const int gemmb = (N / 16 + 3) / 4;          // 782 gemm blocks
    fused_gf_kernel<<<FILLB + gemmb, 256, 0, stream>>>(
        x, src, dst, Wl, Wr, hl, out, cnt, slot, ovf, N, E);

    agg_kernel<<<3 * 4096, 256, 0, stream>>>(hl, cnt, slot, ovf, bl, out, N);
}

// Round 9
// 195.234 us; speedup vs baseline: 2.8204x; 1.0497x over previous
//
#include <hip/hip_runtime.h>
#include <hip/hip_bf16.h>

#define D 96
#define CAP 64          // max tracked degree; slots 32..63 via rare tail loop
#define OVF_MAX 65536   // overflow list capacity (deg > CAP; empty here)
#define FILLB 2048      // fill-role blocks in fused kernel (multiple of 8)
#define GEMMB 782       // gemm-role blocks: (50000/16 + 3) / 4

typedef __attribute__((ext_vector_type(8))) short bf16x8;  // 8 bf16 (4 VGPRs)
typedef __attribute__((ext_vector_type(4))) float f32x4;

__device__ __forceinline__ short f2bf(float f)
{
    union { __hip_bfloat16 h; short s; } u;
    u.h = __float2bfloat16(f);
    return u.s;
}

__device__ __forceinline__ bf16x8 load_frag(const float* p)
{
    float4 lo = *(const float4*)p;
    float4 hi = *(const float4*)(p + 4);
    bf16x8 r;
    r[0] = f2bf(lo.x); r[1] = f2bf(lo.y); r[2] = f2bf(lo.z); r[3] = f2bf(lo.w);
    r[4] = f2bf(hi.x); r[5] = f2bf(hi.y); r[6] = f2bf(hi.z); r[7] = f2bf(hi.w);
    return r;
}

__device__ __forceinline__ float bf_lo(unsigned p) { return __uint_as_float(p << 16); }
__device__ __forceinline__ float bf_hi(unsigned p) { return __uint_as_float(p & 0xFFFF0000u); }

// ---------------------------------------------------------------------------
// K1 (fused): INTERLEAVED role split (R8: fill-first ordering ran the roles
// sequentially). bid%3==2 && bid/3<GEMMB -> gemm; else fill. Resident mix
// ~2.6:1 fill:gemm, so gemm's compute hides in fill's latency shadow.
// Fill: XCD-partitioned by dst range, NO nontemporal (R8 regression: nt
// bypassed L2 and made the 8x dst re-read always miss).
// Gemm: MFMA, no LDS. hl = x@Wl^T (bf16, slice-blocked hl[s][n][c]),
// hr = x@Wr^T (fp32 -> d_out). Layouts verified R4.
// ---------------------------------------------------------------------------
__global__ __launch_bounds__(256) void fused_gf_kernel(
    const float* __restrict__ x, const int* __restrict__ src,
    const int* __restrict__ dst, const float* __restrict__ Wl,
    const float* __restrict__ Wr, __hip_bfloat16* __restrict__ hl,
    float* __restrict__ hr, int* __restrict__ cnt,
    unsigned short* __restrict__ slot, int* __restrict__ ovf,
    int N, int E)
{
    const int bid = blockIdx.x;
    const int gk = bid / 3;
    const bool isGemm = (bid - gk * 3 == 2) && (gk < GEMMB);

    if (!isGemm) {
        // ---- fill role ----
        int g_below = min((bid + 1) / 3, GEMMB);
        int fid = bid - g_below;                 // 0..FILLB-1
        const int g  = fid & 7;
        const int w  = fid >> 3;
        const int NW = FILLB >> 3;               // 256 chunks per group
        const int CS = (E + NW - 1) / NW;
        const int n8 = N >> 3;
        const int lo = g * n8;
        const int hi = (g == 7) ? N : lo + n8;
        const int base = w * CS;
        int lim = E - base; if (lim > CS) lim = CS; if (lim < 0) lim = 0;
        #pragma unroll 4
        for (int i = threadIdx.x; i < lim; i += 256) {
            int e = base + i;
            int d = dst[e];
            if (d >= lo && d < hi) {
                int sv = src[e];
                int pos = atomicAdd(&cnt[d], 1);
                if (pos < CAP) {
                    slot[(size_t)d * CAP + pos] = (unsigned short)sv;
                } else {
                    int o = atomicAdd(&cnt[N], 1);
                    if (o < OVF_MAX) { ovf[2 * o] = d; ovf[2 * o + 1] = sv; }
                }
            }
        }
        return;
    }

    // ---- gemm role ----
    const int gwave = (gk * 256 + threadIdx.x) >> 6;
    const int nrt = N / 16;                      // 3125 (exact)
    if (gwave >= nrt) return;
    const int lane = threadIdx.x & 63;
    const int m = lane & 15, quad = lane >> 4;
    const int row = gwave * 16 + m;

    bf16x8 a[3];
    #pragma unroll
    for (int kt = 0; kt < 3; ++kt)
        a[kt] = load_frag(x + (size_t)row * D + kt * 32 + quad * 8);

    const int orow = gwave * 16 + quad * 4;
    #pragma unroll
    for (int ct = 0; ct < 6; ++ct) {
        int wrow = ct * 16 + m;                  // output col n
        const float* pl = Wl + (size_t)wrow * D + quad * 8;
        const float* pr = Wr + (size_t)wrow * D + quad * 8;
        f32x4 accl = {0.f, 0.f, 0.f, 0.f};
        f32x4 accr = {0.f, 0.f, 0.f, 0.f};
        #pragma unroll
        for (int kt = 0; kt < 3; ++kt) {
            bf16x8 b = load_frag(pl + kt * 32);
            accl = __builtin_amdgcn_mfma_f32_16x16x32_bf16(a[kt], b, accl, 0, 0, 0);
        }
        #pragma unroll
        for (int kt = 0; kt < 3; ++kt) {
            bf16x8 b = load_frag(pr + kt * 32);
            accr = __builtin_amdgcn_mfma_f32_16x16x32_bf16(a[kt], b, accr, 0, 0, 0);
        }
        int col = ct * 16 + m;
        int sl = col >> 5, c = col & 31;         // slice, col-in-slice
        #pragma unroll
        for (int r = 0; r < 4; ++r) {
            int node = orow + r;
            hl[((size_t)sl * N + node) * 32 + c] = __float2bfloat16(accl[r]);
            hr[(size_t)node * D + col] = accr[r];
        }
    }
}

// ---------------------------------------------------------------------------
// K2: gather-mean + bias + relu, feature-sliced (3 x 32 features = 64 B rows;
// block-id-major slice order keeps one 3.2 MB slice per XCD L2). Wave = node.
// R9: 16-B gathers. Lane = (edge q=lane>>2, quarter r4=lane&3): one wave-load
// covers 16 edges x 64 B = 1 KB (R8: 4 edges/instruction). 8 accs/lane,
// shfl_xor 4/8/16/32 reduce, float4 epilogue by lanes 0-3.
// ---------------------------------------------------------------------------
__global__ __launch_bounds__(256) void agg_kernel(
    const __hip_bfloat16* __restrict__ hl, const int* __restrict__ cnt,
    const unsigned short* __restrict__ slot, const int* __restrict__ ovf,
    const float* __restrict__ bl, float* __restrict__ out, int N)
{
    const int lane = threadIdx.x & 63;
    const int wv = threadIdx.x >> 6;
    const int s  = blockIdx.x >> 12;             // slice 0..2 (4096 blocks each)
    const int bb = blockIdx.x & 4095;
    const int q  = lane >> 2;                    // edge slot in chunk: 0..15
    const int r4 = lane & 3;                     // feature quarter
    const int ovfn = min(cnt[N], OVF_MAX);
    const unsigned short* hs = (const unsigned short*)hl + (size_t)s * N * 32;
    const int o = s * 32 + r4 * 8;               // thread-constant
    const float4 bia0 = *(const float4*)(bl + o);
    const float4 bia1 = *(const float4*)(bl + o + 4);

    for (int n = bb * 4 + wv; n < N; n += 4096 * 4) {
        int deg = cnt[n];
        int dc = min(deg, CAP);
        int dp = min(dc, 32);
        const unsigned* sp = (const unsigned*)(slot + (size_t)n * CAP);
        unsigned sid = (lane < 32) ? sp[lane] : 0u;  // dword l = slots 2l,2l+1
        float a[8] = {0.f, 0.f, 0.f, 0.f, 0.f, 0.f, 0.f, 0.f};
        int nch = (dp + 15) >> 4;                // 0..2 chunks of 16 edges
        for (int c = 0; c < nch; ++c) {
            int idx = c * 16 + q;
            unsigned dw = __shfl(sid, c * 8 + (q >> 1));
            bool act = idx < dp;
            int nb = act ? ((q & 1) ? (int)(dw >> 16) : (int)(dw & 0xFFFFu)) : 0;
            uint4 p = *(const uint4*)(hs + (size_t)nb * 32 + r4 * 8);
            if (!act) { p.x = 0u; p.y = 0u; p.z = 0u; p.w = 0u; }
            a[0] += bf_lo(p.x); a[1] += bf_hi(p.x);
            a[2] += bf_lo(p.y); a[3] += bf_hi(p.y);
            a[4] += bf_lo(p.z); a[5] += bf_hi(p.z);
            a[6] += bf_lo(p.w); a[7] += bf_hi(p.w);
        }
        if (dc > 32) {                           // rare (Poisson(16): ~1e-4)
            for (int idx = 32 + q; idx < dc; idx += 16) {
                unsigned dw = sp[idx >> 1];
                int nb = (idx & 1) ? (int)(dw >> 16) : (int)(dw & 0xFFFFu);
                uint4 p = *(const uint4*)(hs + (size_t)nb * 32 + r4 * 8);
                a[0] += bf_lo(p.x); a[1] += bf_hi(p.x);
                a[2] += bf_lo(p.y); a[3] += bf_hi(p.y);
                a[4] += bf_lo(p.z); a[5] += bf_hi(p.z);
                a[6] += bf_lo(p.w); a[7] += bf_hi(p.w);
            }
        }
        // reduce over q (lanes sharing r4): xor lane bits 2..5
        #pragma unroll
        for (int off = 4; off < 64; off <<= 1) {
            #pragma unroll
            for (int k = 0; k < 8; ++k) a[k] += __shfl_xor(a[k], off);
        }
        if (lane < 4) {                          // lane == r4 here
            if (ovfn) {                          // exactness guard, empty here
                for (int kk = 0; kk < ovfn; ++kk) {
                    if (ovf[2 * kk] == n) {
                        int nb = ovf[2 * kk + 1];
                        uint4 p = *(const uint4*)(hs + (size_t)nb * 32 + r4 * 8);
                        a[0] += bf_lo(p.x); a[1] += bf_hi(p.x);
                        a[2] += bf_lo(p.y); a[3] += bf_hi(p.y);
                        a[4] += bf_lo(p.z); a[5] += bf_hi(p.z);
                        a[6] += bf_lo(p.w); a[7] += bf_hi(p.w);
                    }
                }
            }
            float inv = 1.0f / fmaxf((float)deg, 1.0f);
            size_t base = (size_t)n * D + o;
            float4 u0 = *(const float4*)(out + base);
            float4 u1 = *(const float4*)(out + base + 4);
            u0.x = fmaxf(a[0] * inv + bia0.x + u0.x, 0.f);
            u0.y = fmaxf(a[1] * inv + bia0.y + u0.y, 0.f);
            u0.z = fmaxf(a[2] * inv + bia0.z + u0.z, 0.f);
            u0.w = fmaxf(a[3] * inv + bia0.w + u0.w, 0.f);
            u1.x = fmaxf(a[4] * inv + bia1.x + u1.x, 0.f);
            u1.y = fmaxf(a[5] * inv + bia1.y + u1.y, 0.f);
            u1.z = fmaxf(a[6] * inv + bia1.z + u1.z, 0.f);
            u1.w = fmaxf(a[7] * inv + bia1.w + u1.w, 0.f);
            *(float4*)(out + base)     = u0;
            *(float4*)(out + base + 4) = u1;
        }
    }
}

extern "C" void kernel_launch(void* const* d_in, const int* in_sizes, int n_in,
                              void* d_out, int out_size, void* d_ws, size_t ws_size,
                              hipStream_t stream)
{
    const float* x  = (const float*)d_in[0];
    const int*   ei = (const int*)d_in[1];   // [2, E]: src row then dst row
    const float* Wl = (const float*)d_in[2];
    const float* bl = (const float*)d_in[3];
    const float* Wr = (const float*)d_in[4];
    float* out = (float*)d_out;

    const int N = in_sizes[0] / D;   // 50000
    const int E = in_sizes[1] / 2;   // 800000
    const int* src = ei;
    const int* dst = ei + E;

    // ws layout (hl FIRST for 64-B alignment of uint4 gathers):
    // hl[3*N*32] bf16 (9.6 MB), slot[N*CAP] u16 (6.4 MB), cnt[N+1], ovf[2*OVF]
    __hip_bfloat16* hl = (__hip_bfloat16*)d_ws;
    unsigned short* slot = (unsigned short*)(hl + (size_t)3 * N * 32);
    int* cnt = (int*)(slot + (size_t)N * CAP);
    int* ovf = cnt + (N + 1);

    hipMemsetAsync(cnt, 0, (size_t)(N + 1) * sizeof(int), stream);

    fused_gf_kernel<<<FILLB + GEMMB, 256, 0, stream>>>(
        x, src, dst, Wl, Wr, hl, out, cnt, slot, ovf, N, E);

    agg_kernel<<<3 * 4096, 256, 0, stream>>>(hl, cnt, slot, ovf, bl, out, N);
}